// Round 2
// baseline (159.021 us; speedup 1.0000x reference)
//
#include <hip/hip_runtime.h>

#define LSZ 1024
#define EPS 1e-8f
#define NBLK 2048
#define SPT 2                      // sites per thread; NBLK*256*SPT == L*L exactly
#define STRIDE (NBLK * 256)       // 524288 threads

typedef float vfloat4 __attribute__((ext_vector_type(4)));

struct c32 { float re, im; };

__device__ __forceinline__ c32 cmul(c32 a, c32 b) {
    return { a.re * b.re - a.im * b.im, a.re * b.im + a.im * b.re };
}
// a * conj(b)
__device__ __forceinline__ c32 cmulc(c32 a, c32 b) {
    return { a.re * b.re + a.im * b.im, a.im * b.re - a.re * b.im };
}
__device__ __forceinline__ c32 cadd(c32 a, c32 b) {
    return { a.re + b.re, a.im + b.im };
}

// g = cos(n) I + i sinc(n) (theta . sigma). Native sin/cos/rcp: theta norms
// are <= ~7 (3 gaussians), safely in fast range; error ~1e-6 << 8e-2 thresh.
__device__ __forceinline__ void make_g(float tx, float ty, float tz, c32 g[2][2]) {
    float n2 = tx * tx + ty * ty + tz * tz;
    float n  = __builtin_amdgcn_sqrtf(n2);
    float cc = __cosf(n);
    float sn = __sinf(n);
    float s  = (n > EPS) ? (sn * __builtin_amdgcn_rcpf(n)) : 1.0f;
    float a1 = s * tx, a2 = s * ty, a3 = s * tz;
    g[0][0] = {  cc,  a3 };
    g[0][1] = {  a2,  a1 };
    g[1][0] = { -a2,  a1 };
    g[1][1] = {  cc, -a3 };
}

// Ut = g @ M @ gn^dagger ; return sum |P - Ut|^2 over the 4 entries
__device__ __forceinline__ float site_mu_loss(const c32 g[2][2], const c32 gn[2][2],
                                              vfloat4 m0, vfloat4 m1,
                                              vfloat4 p0, vfloat4 p1) {
    c32 M[2][2] = { { { m0.x, m0.y }, { m0.z, m0.w } },
                    { { m1.x, m1.y }, { m1.z, m1.w } } };
    c32 P[2][2] = { { { p0.x, p0.y }, { p0.z, p0.w } },
                    { { p1.x, p1.y }, { p1.z, p1.w } } };
    c32 T[2][2];
#pragma unroll
    for (int a = 0; a < 2; ++a)
#pragma unroll
        for (int cc = 0; cc < 2; ++cc)
            T[a][cc] = cadd(cmul(g[a][0], M[0][cc]), cmul(g[a][1], M[1][cc]));

    float acc = 0.0f;
#pragma unroll
    for (int a = 0; a < 2; ++a)
#pragma unroll
        for (int d = 0; d < 2; ++d) {
            c32 ut = cadd(cmulc(T[a][0], gn[d][0]), cmulc(T[a][1], gn[d][1]));
            float dr = P[a][d].re - ut.re;
            float di = P[a][d].im - ut.im;
            acc += dr * dr + di * di;
        }
    return acc;
}

// MLP-forced site loss. Every variant so far (R1-R8 one-shot, R9 prefetch,
// R10 high-occupancy) ran ~49 us because hipcc sinks loads to just-before-use
// (VGPR_Count 32-36 proves it): each site became ~6 dependent memory round
// trips and no occupancy level hides that chain. The empty asm fences below
// are read-write on every loaded value: loads cannot sink below them, compute
// cannot hoist above them -> all 17 loads (8x dwordx4 + 9x dword) issue as one
// batch with a single waitcnt region per site. ~10 KB in flight per wave.
__device__ __forceinline__ float site_loss(int idx,
                                           const float* __restrict__ theta,
                                           const float* __restrict__ U_pred,
                                           const float* __restrict__ U_true) {
    int x = idx >> 10, y = idx & (LSZ - 1);
    int xp = (x + 1) & (LSZ - 1), yp = (y + 1) & (LSZ - 1);

    const float* ta = theta + 3 * (x  * LSZ + y);
    const float* tb = theta + 3 * (xp * LSZ + y);
    const float* tc = theta + 3 * (x  * LSZ + yp);
    const vfloat4* Ut4 = (const vfloat4*)U_true + (size_t)idx * 4;
    const vfloat4* Up4 = (const vfloat4*)U_pred + (size_t)idx * 4;

    vfloat4 t0 = Ut4[0], t1 = Ut4[1], t2 = Ut4[2], t3 = Ut4[3];
    vfloat4 p0 = Up4[0], p1 = Up4[1], p2 = Up4[2], p3 = Up4[3];
    float a0 = ta[0], a1 = ta[1], a2 = ta[2];
    float b0 = tb[0], b1 = tb[1], b2 = tb[2];
    float c0 = tc[0], c1 = tc[1], c2 = tc[2];

    // Scheduling fences: all loads above must complete issue before any
    // compute below can be scheduled. (asm volatile stmts keep their relative
    // order; "+v" ties each value's consumer to the fence output.)
    asm volatile("" : "+v"(t0), "+v"(t1), "+v"(t2), "+v"(t3),
                      "+v"(p0), "+v"(p1), "+v"(p2), "+v"(p3));
    asm volatile("" : "+v"(a0), "+v"(a1), "+v"(a2),
                      "+v"(b0), "+v"(b1), "+v"(b2),
                      "+v"(c0), "+v"(c1), "+v"(c2));

    c32 g[2][2], gn[2][2];
    make_g(a0, a1, a2, g);
    make_g(b0, b1, b2, gn);
    float acc = site_mu_loss(g, gn, t0, t1, p0, p1);   // mu = 0
    make_g(c0, c1, c2, gn);
    acc += site_mu_loss(g, gn, t2, t3, p2, p3);        // mu = 1
    return acc;
}

__global__ __launch_bounds__(256, 8) void gauge_loss_kernel(
    const float* __restrict__ theta,
    const float* __restrict__ U_pred,
    const float* __restrict__ U_true,
    float* __restrict__ partial) {
    const int tid = blockIdx.x * 256 + threadIdx.x;

    float acc = 0.0f;
#pragma unroll
    for (int s = 0; s < SPT; ++s)
        acc += site_loss(tid + s * STRIDE, theta, U_pred, U_true);

    // fold: mean over 4 entries (1/4) and final /(L*L*2)
    acc *= (1.0f / (8.0f * (float)LSZ * (float)LSZ));

    // wave (64-lane) shuffle reduction
#pragma unroll
    for (int off = 32; off > 0; off >>= 1)
        acc += __shfl_down(acc, off, 64);

    __shared__ float wave_sums[4];
    int lane = threadIdx.x & 63;
    int wave = threadIdx.x >> 6;
    if (lane == 0) wave_sums[wave] = acc;
    __syncthreads();
    if (threadIdx.x == 0)
        partial[blockIdx.x] = wave_sums[0] + wave_sums[1] + wave_sums[2] + wave_sums[3];
}

__global__ __launch_bounds__(256) void reduce_kernel(const float* __restrict__ partial,
                                                     float* __restrict__ out) {
    float s = 0.0f;
#pragma unroll
    for (int i = 0; i < NBLK / 256; ++i)
        s += partial[i * 256 + threadIdx.x];

#pragma unroll
    for (int off = 32; off > 0; off >>= 1)
        s += __shfl_down(s, off, 64);

    __shared__ float wave_sums[4];
    int lane = threadIdx.x & 63;
    int wave = threadIdx.x >> 6;
    if (lane == 0) wave_sums[wave] = s;
    __syncthreads();
    if (threadIdx.x == 0)
        out[0] = wave_sums[0] + wave_sums[1] + wave_sums[2] + wave_sums[3];
}

extern "C" void kernel_launch(void* const* d_in, const int* in_sizes, int n_in,
                              void* d_out, int out_size, void* d_ws, size_t ws_size,
                              hipStream_t stream) {
    const float* theta  = (const float*)d_in[0];
    const float* U_pred = (const float*)d_in[1];
    const float* U_true = (const float*)d_in[2];
    float* out = (float*)d_out;
    float* partial = (float*)d_ws;  // NBLK floats

    gauge_loss_kernel<<<NBLK, 256, 0, stream>>>(theta, U_pred, U_true, partial);
    reduce_kernel<<<1, 256, 0, stream>>>(partial, out);
}

// Round 3
// 157.810 us; speedup vs baseline: 1.0077x; 1.0077x over previous
//
#include <hip/hip_runtime.h>

#define LSZ 1024
#define EPS 1e-8f
#define NBLK 2048
#define SPT 2                      // sites per thread; NBLK*256*SPT == L*L exactly
#define STRIDE (NBLK * 256)       // 524288 threads

typedef float vfloat4 __attribute__((ext_vector_type(4)));

struct c32 { float re, im; };

__device__ __forceinline__ c32 cmul(c32 a, c32 b) {
    return { a.re * b.re - a.im * b.im, a.re * b.im + a.im * b.re };
}
// a * conj(b)
__device__ __forceinline__ c32 cmulc(c32 a, c32 b) {
    return { a.re * b.re + a.im * b.im, a.im * b.re - a.re * b.im };
}
__device__ __forceinline__ c32 cadd(c32 a, c32 b) {
    return { a.re + b.re, a.im + b.im };
}

// g = cos(n) I + i sinc(n) (theta . sigma). Native sin/cos/rcp: theta norms
// are <= ~7 (3 gaussians), safely in fast range; error ~1e-6 << 8e-2 thresh.
__device__ __forceinline__ void make_g(float tx, float ty, float tz, c32 g[2][2]) {
    float n2 = tx * tx + ty * ty + tz * tz;
    float n  = __builtin_amdgcn_sqrtf(n2);
    float cc = __cosf(n);
    float sn = __sinf(n);
    float s  = (n > EPS) ? (sn * __builtin_amdgcn_rcpf(n)) : 1.0f;
    float a1 = s * tx, a2 = s * ty, a3 = s * tz;
    g[0][0] = {  cc,  a3 };
    g[0][1] = {  a2,  a1 };
    g[1][0] = { -a2,  a1 };
    g[1][1] = {  cc, -a3 };
}

// Ut = g @ M @ gn^dagger ; return sum |P - Ut|^2 over the 4 entries
__device__ __forceinline__ float site_mu_loss(const c32 g[2][2], const c32 gn[2][2],
                                              vfloat4 m0, vfloat4 m1,
                                              vfloat4 p0, vfloat4 p1) {
    c32 M[2][2] = { { { m0.x, m0.y }, { m0.z, m0.w } },
                    { { m1.x, m1.y }, { m1.z, m1.w } } };
    c32 P[2][2] = { { { p0.x, p0.y }, { p0.z, p0.w } },
                    { { p1.x, p1.y }, { p1.z, p1.w } } };
    c32 T[2][2];
#pragma unroll
    for (int a = 0; a < 2; ++a)
#pragma unroll
        for (int cc = 0; cc < 2; ++cc)
            T[a][cc] = cadd(cmul(g[a][0], M[0][cc]), cmul(g[a][1], M[1][cc]));

    float acc = 0.0f;
#pragma unroll
    for (int a = 0; a < 2; ++a)
#pragma unroll
        for (int d = 0; d < 2; ++d) {
            c32 ut = cadd(cmulc(T[a][0], gn[d][0]), cmulc(T[a][1], gn[d][1]));
            float dr = P[a][d].re - ut.re;
            float di = P[a][d].im - ut.im;
            acc += dr * dr + di * di;
        }
    return acc;
}

// ACCESS-PATTERN fix (R3). All prior variants (one-shot, prefetch, occupancy,
// fenced batches) pinned at ~50 us with identical per-instruction address
// patterns: per-site dwordx4 at 64 B lane-stride = 64 cache lines touched per
// instruction (4 KB span) vs 16 for lane-contiguous — ~620 L1 line-transactions
// per site-wave vs 164 unique lines. Theory: per-CU TA/L1 request throughput is
// the choke (explains VALUBusy 13%, occupancy-insensitivity, batch-insensitivity).
// Fix: wave-cooperative staging. Each wave loads its 64 sites' U data with
// lane-CONTIGUOUS dwordx4 (16 lines/instr, memcpy pattern) into a private LDS
// region, XOR-swizzled so the per-site ds_read_b128 readback is conflict-free.
// Wave-local LDS => no barriers. theta: dwordx3 (1 instr) instead of 3 dwords.
__global__ __launch_bounds__(256, 4) void gauge_loss_kernel(
    const float* __restrict__ theta,
    const float* __restrict__ U_pred,
    const float* __restrict__ U_true,
    float* __restrict__ partial) {
    // 4 waves x (U_true 1024 + U_pred 1024 words) = 32 KB
    __shared__ __align__(16) float lds[8192];
    const int tid  = blockIdx.x * 256 + threadIdx.x;
    const int lane = threadIdx.x & 63;
    const int wv   = threadIdx.x >> 6;
    float* lt = lds + wv * 2048;
    float* lp = lt + 1024;

    float acc = 0.0f;
#pragma unroll
    for (int it = 0; it < SPT; ++it) {
        const int wbase = (tid - lane) + it * STRIDE;   // wave's first site, 64-aligned

        // ---- stage: 64 sites x 64 B per array, lane-contiguous global reads ----
        const vfloat4* T4 = (const vfloat4*)U_true + (size_t)wbase * 4;
        const vfloat4* P4 = (const vfloat4*)U_pred + (size_t)wbase * 4;
#pragma unroll
        for (int c = 0; c < 4; ++c) {
            vfloat4 vt = T4[c * 64 + lane];             // 1 KB/instr, 16 lines
            vfloat4 vp = P4[c * 64 + lane];
            const int s = c * 16 + (lane >> 2);         // site-in-wave this 16B belongs to
            const int w = s * 16 + (((lane & 3) ^ ((s >> 1) & 3)) << 2);  // swizzled word
            *(vfloat4*)(lt + w) = vt;                   // ds_write_b128, conflict-free
            *(vfloat4*)(lp + w) = vp;
        }

        // ---- per-site compute (thread = site wbase+lane) ----
        const int site = wbase + lane;
        const int x = site >> 10, y = site & (LSZ - 1);
        const int xp = (x + 1) & (LSZ - 1), yp = (y + 1) & (LSZ - 1);
        const float3 a  = *(const float3*)(theta + 3 * (x  * LSZ + y));
        const float3 b  = *(const float3*)(theta + 3 * (xp * LSZ + y));
        const float3 ct = *(const float3*)(theta + 3 * (x  * LSZ + yp));

        const int sb = lane * 16;
        const int k  = (lane >> 1) & 3;                 // same XOR as write side
        vfloat4 t0 = *(const vfloat4*)(lt + sb + ((0 ^ k) << 2));
        vfloat4 t1 = *(const vfloat4*)(lt + sb + ((1 ^ k) << 2));
        vfloat4 t2 = *(const vfloat4*)(lt + sb + ((2 ^ k) << 2));
        vfloat4 t3 = *(const vfloat4*)(lt + sb + ((3 ^ k) << 2));
        vfloat4 p0 = *(const vfloat4*)(lp + sb + ((0 ^ k) << 2));
        vfloat4 p1 = *(const vfloat4*)(lp + sb + ((1 ^ k) << 2));
        vfloat4 p2 = *(const vfloat4*)(lp + sb + ((2 ^ k) << 2));
        vfloat4 p3 = *(const vfloat4*)(lp + sb + ((3 ^ k) << 2));

        c32 g[2][2], gn[2][2];
        make_g(a.x, a.y, a.z, g);
        make_g(b.x, b.y, b.z, gn);
        acc += site_mu_loss(g, gn, t0, t1, p0, p1);     // mu = 0
        make_g(ct.x, ct.y, ct.z, gn);
        acc += site_mu_loss(g, gn, t2, t3, p2, p3);     // mu = 1
    }

    // fold: mean over 4 entries (1/4) and final /(L*L*2)
    acc *= (1.0f / (8.0f * (float)LSZ * (float)LSZ));

    // wave (64-lane) shuffle reduction
#pragma unroll
    for (int off = 32; off > 0; off >>= 1)
        acc += __shfl_down(acc, off, 64);

    __shared__ float wave_sums[4];
    if (lane == 0) wave_sums[wv] = acc;
    __syncthreads();
    if (threadIdx.x == 0)
        partial[blockIdx.x] = wave_sums[0] + wave_sums[1] + wave_sums[2] + wave_sums[3];
}

__global__ __launch_bounds__(256) void reduce_kernel(const float* __restrict__ partial,
                                                     float* __restrict__ out) {
    float s = 0.0f;
#pragma unroll
    for (int i = 0; i < NBLK / 256; ++i)
        s += partial[i * 256 + threadIdx.x];

#pragma unroll
    for (int off = 32; off > 0; off >>= 1)
        s += __shfl_down(s, off, 64);

    __shared__ float wave_sums[4];
    int lane = threadIdx.x & 63;
    int wave = threadIdx.x >> 6;
    if (lane == 0) wave_sums[wave] = s;
    __syncthreads();
    if (threadIdx.x == 0)
        out[0] = wave_sums[0] + wave_sums[1] + wave_sums[2] + wave_sums[3];
}

extern "C" void kernel_launch(void* const* d_in, const int* in_sizes, int n_in,
                              void* d_out, int out_size, void* d_ws, size_t ws_size,
                              hipStream_t stream) {
    const float* theta  = (const float*)d_in[0];
    const float* U_pred = (const float*)d_in[1];
    const float* U_true = (const float*)d_in[2];
    float* out = (float*)d_out;
    float* partial = (float*)d_ws;  // NBLK floats

    gauge_loss_kernel<<<NBLK, 256, 0, stream>>>(theta, U_pred, U_true, partial);
    reduce_kernel<<<1, 256, 0, stream>>>(partial, out);
}